// Round 9
// baseline (335.732 us; speedup 1.0000x reference)
//
#include <hip/hip_runtime.h>
#include <hip/hip_bf16.h>

__device__ __forceinline__ float eluf(float x) {
    return x > 0.f ? x : expm1f(x);
}

// C[M,N] = act( A[M,K] @ B[N,K]^T + bias ), ACT: 0 none, 1 relu.
// SPLIT: raw partial to C + blockIdx.z*M*N.  BM=128 TM=8, BN=64 TN=4, BK=16.
template<int ACT, bool BIAS, bool SPLIT>
__global__ __launch_bounds__(256) void gemm256(
    const float* __restrict__ A, const float* __restrict__ B,
    const float* __restrict__ bias, float* __restrict__ C,
    int M, int N, int K, int kChunk)
{
    constexpr int BM = 128, BN = 64, BK = 16;
    __shared__ float As[BK][BM + 4];
    __shared__ float Bs[BK][BN + 4];
    const int t  = threadIdx.x;
    const int tx = t & 15;
    const int ty = t >> 4;
    const int m0 = blockIdx.x * BM;
    const int n0 = blockIdx.y * BN;
    const int kBeg = SPLIT ? blockIdx.z * kChunk : 0;
    const int kEnd = SPLIT ? kBeg + kChunk : K;

    float acc[8][4] = {};

    for (int k0 = kBeg; k0 < kEnd; k0 += BK) {
        #pragma unroll
        for (int i = 0; i < 2; ++i) {
            int idx = t + i * 256;
            int row = idx >> 2, c4 = idx & 3;
            int grow = m0 + row;
            float4 v = make_float4(0.f, 0.f, 0.f, 0.f);
            if (grow < M) v = *(const float4*)&A[(size_t)grow * K + k0 + c4 * 4];
            As[c4 * 4 + 0][row] = v.x; As[c4 * 4 + 1][row] = v.y;
            As[c4 * 4 + 2][row] = v.z; As[c4 * 4 + 3][row] = v.w;
        }
        {
            int n = t >> 2, c4 = t & 3;
            float4 v = *(const float4*)&B[(size_t)(n0 + n) * K + k0 + c4 * 4];
            Bs[c4 * 4 + 0][n] = v.x; Bs[c4 * 4 + 1][n] = v.y;
            Bs[c4 * 4 + 2][n] = v.z; Bs[c4 * 4 + 3][n] = v.w;
        }
        __syncthreads();
        #pragma unroll
        for (int k = 0; k < BK; ++k) {
            float a[8], b[4];
            *(float4*)&a[0] = *(const float4*)&As[k][ty * 8];
            *(float4*)&a[4] = *(const float4*)&As[k][ty * 8 + 4];
            *(float4*)&b[0] = *(const float4*)&Bs[k][tx * 4];
            #pragma unroll
            for (int i = 0; i < 8; ++i)
                #pragma unroll
                for (int j = 0; j < 4; ++j)
                    acc[i][j] = fmaf(a[i], b[j], acc[i][j]);
        }
        __syncthreads();
    }

    float* Cw = SPLIT ? C + (size_t)blockIdx.z * M * N : C;
    #pragma unroll
    for (int i = 0; i < 8; ++i) {
        int row = m0 + ty * 8 + i;
        if (row >= M) continue;
        float4 v;
        float* vp = (float*)&v;
        #pragma unroll
        for (int j = 0; j < 4; ++j) {
            float xv = acc[i][j];
            if (!SPLIT) {
                if (BIAS) xv += bias[n0 + tx * 4 + j];
                if (ACT == 1) xv = fmaxf(xv, 0.f);
            }
            vp[j] = xv;
        }
        *(float4*)&Cw[(size_t)row * N + n0 + tx * 4] = v;
    }
}

// Fused: z2[m0:m0+64, 0:64] = elu( gx_tile @ W1^T ) @ W2^T  (K=N1=128, N2=64)
// gx tile loaded coalesced once; both GEMMs run from LDS; h1 never stored.
__global__ __launch_bounds__(256) void gemm12_fused(
    const float* __restrict__ gx, const float* __restrict__ W1,
    const float* __restrict__ W2, float* __restrict__ z2, int N)
{
    __shared__ float As[64][132];   // 33.8 KB [row][k]
    __shared__ float Ws[16][132];   //  8.4 KB [k][n]
    const int t  = threadIdx.x;
    const int m0 = blockIdx.x * 64;

    // phase A: load own 64 rows of gx
    for (int idx = t; idx < 2048; idx += 256) {
        int row = idx >> 5, c4 = idx & 31;
        int grow = m0 + row;
        float4 v = make_float4(0.f, 0.f, 0.f, 0.f);
        if (grow < N) v = *(const float4*)&gx[(size_t)grow * 128 + c4 * 4];
        *(float4*)&As[row][c4 * 4] = v;
    }
    __syncthreads();

    const int tx = t & 15, ty = t >> 4;   // rows ty*4+i, cols tx+16*j

    // phase B: GEMM1 (K=128 -> 128 cols), W1 streamed 16-k tiles
    float acc[4][8] = {};
    for (int k0 = 0; k0 < 128; k0 += 16) {
        for (int idx = t; idx < 512; idx += 256) {
            int n = idx >> 2, kq = idx & 3;
            float4 v = *(const float4*)&W1[(size_t)n * 128 + k0 + kq * 4];
            Ws[kq * 4 + 0][n] = v.x; Ws[kq * 4 + 1][n] = v.y;
            Ws[kq * 4 + 2][n] = v.z; Ws[kq * 4 + 3][n] = v.w;
        }
        __syncthreads();
        #pragma unroll
        for (int k = 0; k < 16; ++k) {
            float a[4], w[8];
            #pragma unroll
            for (int i = 0; i < 4; ++i) a[i] = As[ty * 4 + i][k0 + k];
            #pragma unroll
            for (int j = 0; j < 8; ++j) w[j] = Ws[k][tx + 16 * j];
            #pragma unroll
            for (int i = 0; i < 4; ++i)
                #pragma unroll
                for (int j = 0; j < 8; ++j)
                    acc[i][j] = fmaf(a[i], w[j], acc[i][j]);
        }
        __syncthreads();
    }

    // phase C: As = elu(h1 tile)
    #pragma unroll
    for (int i = 0; i < 4; ++i)
        #pragma unroll
        for (int j = 0; j < 8; ++j)
            As[ty * 4 + i][tx + 16 * j] = eluf(acc[i][j]);
    __syncthreads();

    // phase D: GEMM2 (K=128 -> 64 cols), W2 streamed
    float acc2[4][4] = {};
    for (int k0 = 0; k0 < 128; k0 += 16) {
        {
            int idx = t;   // 64 n x 4 kq = 256
            int n = idx >> 2, kq = idx & 3;
            float4 v = *(const float4*)&W2[(size_t)n * 128 + k0 + kq * 4];
            Ws[kq * 4 + 0][n] = v.x; Ws[kq * 4 + 1][n] = v.y;
            Ws[kq * 4 + 2][n] = v.z; Ws[kq * 4 + 3][n] = v.w;
        }
        __syncthreads();
        #pragma unroll
        for (int k = 0; k < 16; ++k) {
            float a[4], w[4];
            #pragma unroll
            for (int i = 0; i < 4; ++i) a[i] = As[ty * 4 + i][k0 + k];
            #pragma unroll
            for (int j = 0; j < 4; ++j) w[j] = Ws[k][tx + 16 * j];
            #pragma unroll
            for (int i = 0; i < 4; ++i)
                #pragma unroll
                for (int j = 0; j < 4; ++j)
                    acc2[i][j] = fmaf(a[i], w[j], acc2[i][j]);
        }
        __syncthreads();
    }

    // epilogue: stage z2 tile through As cols 0..63, then float4 stores
    #pragma unroll
    for (int i = 0; i < 4; ++i)
        #pragma unroll
        for (int j = 0; j < 4; ++j)
            As[ty * 4 + i][tx + 16 * j] = acc2[i][j];
    __syncthreads();
    for (int idx = t; idx < 1024; idx += 256) {
        int row = idx >> 4, c4 = idx & 15;
        int grow = m0 + row;
        if (grow < N)
            *(float4*)&z2[(size_t)grow * 64 + c4 * 4] = *(const float4*)&As[row][c4 * 4];
    }
}

// C[i] = relu( sum_z part[z][i] + bias[i % N] ), float4-wide
__global__ __launch_bounds__(256) void reduce_bias_relu(
    const float* __restrict__ part, const float* __restrict__ bias,
    float* __restrict__ C, int MN4, int N, int KS)
{
    int i = blockIdx.x * 256 + threadIdx.x;
    if (i >= MN4) return;
    float4 s = *(const float4*)&part[(size_t)i * 4];
    for (int z = 1; z < KS; ++z) {
        float4 p = *(const float4*)&part[(size_t)z * MN4 * 4 + (size_t)i * 4];
        s.x += p.x; s.y += p.y; s.z += p.z; s.w += p.w;
    }
    float4 bv = *(const float4*)&bias[(i * 4) & (N - 1)];
    s.x = fmaxf(s.x + bv.x, 0.f);
    s.y = fmaxf(s.y + bv.y, 0.f);
    s.z = fmaxf(s.z + bv.z, 0.f);
    s.w = fmaxf(s.w + bv.w, 0.f);
    *(float4*)&C[(size_t)i * 4] = s;
}

// ---------- init: zero cnt + compute graph bounds (batch sorted) ----------
__global__ __launch_bounds__(256) void init_kernel(
    const int* __restrict__ batch, int* __restrict__ cnt,
    int* __restrict__ bstart, int N, int B)
{
    int i = blockIdx.x * 256 + threadIdx.x;
    if (i < N) cnt[i] = 0;
    if (i <= B) {
        int lo = 0, hi = N;
        while (lo < hi) {
            int mid = (lo + hi) >> 1;
            if (batch[mid] < i) lo = mid + 1; else hi = mid;
        }
        bstart[i] = lo;
    }
}

// ---------- one-pass ELL build ----------
__global__ __launch_bounds__(256) void scatter_ell(
    const int* __restrict__ row, const int* __restrict__ col,
    int* __restrict__ cnt, int* __restrict__ ell, int E)
{
    int e = blockIdx.x * 256 + threadIdx.x;
    if (e >= E) return;
    int r = row[e];
    int p = atomicAdd(&cnt[r], 1);
    if (p < 64) ell[(size_t)r * 64 + p] = col[e];
}

// ---------- gather-sum over ELL (layer 1, D=128) ----------
template<int DQ>
__global__ __launch_bounds__(256) void gather_sum_ell(
    const int* __restrict__ ell, const int* __restrict__ cnt,
    const float* __restrict__ z, float* __restrict__ h, int N)
{
    constexpr int GPB = 256 / DQ;
    constexpr int D = DQ * 4;
    const int node = blockIdx.x * GPB + threadIdx.x / DQ;
    const int lane = threadIdx.x % DQ;
    if (node >= N) return;
    const int deg = cnt[node];
    const size_t base = (size_t)node * 64;
    float ax = 0.f, ay = 0.f, az = 0.f, aw = 0.f;
    for (int b0 = 0; b0 < deg; b0 += DQ) {
        int idx = b0 + lane;
        int c = (idx < deg) ? ell[base + idx] : 0;
        int m = min(DQ, deg - b0);
        int q = 0;
        for (; q + 4 <= m; q += 4) {
            int c0 = __shfl(c, q + 0, DQ), c1 = __shfl(c, q + 1, DQ);
            int c2 = __shfl(c, q + 2, DQ), c3 = __shfl(c, q + 3, DQ);
            float4 v0 = *(const float4*)&z[(size_t)c0 * D + lane * 4];
            float4 v1 = *(const float4*)&z[(size_t)c1 * D + lane * 4];
            float4 v2 = *(const float4*)&z[(size_t)c2 * D + lane * 4];
            float4 v3 = *(const float4*)&z[(size_t)c3 * D + lane * 4];
            ax += (v0.x + v1.x) + (v2.x + v3.x);
            ay += (v0.y + v1.y) + (v2.y + v3.y);
            az += (v0.z + v1.z) + (v2.z + v3.z);
            aw += (v0.w + v1.w) + (v2.w + v3.w);
        }
        for (; q < m; ++q) {
            int cj = __shfl(c, q, DQ);
            float4 v = *(const float4*)&z[(size_t)cj * D + lane * 4];
            ax += v.x; ay += v.y; az += v.z; aw += v.w;
        }
    }
    *(float4*)&h[(size_t)node * D + lane * 4] = make_float4(ax, ay, az, aw);
}

// ---------- fused gather2 + mean-pool ----------
// block b: g[b] = (1/n_b) * sum over nodes in [bstart[b],bstart[b+1])
//                 of sum over their ELL edges of z2[col]   (D=64)
__global__ __launch_bounds__(256) void pool_gather(
    const int* __restrict__ ell, const int* __restrict__ cnt,
    const int* __restrict__ bstart, const float* __restrict__ z2,
    float* __restrict__ g)
{
    __shared__ float4 s[256];
    const int b    = blockIdx.x;
    const int lane = threadIdx.x & 15;   // float4 column of D=64
    const int grp  = threadIdx.x >> 4;   // 16 node-groups
    const int start = bstart[b], end = bstart[b + 1];

    float ax = 0.f, ay = 0.f, az = 0.f, aw = 0.f;
    for (int node = start + grp; node < end; node += 16) {
        const int deg = cnt[node];
        const size_t base = (size_t)node * 64;
        for (int b0 = 0; b0 < deg; b0 += 16) {
            int idx = b0 + lane;
            int c = (idx < deg) ? ell[base + idx] : 0;
            int m = min(16, deg - b0);
            int q = 0;
            for (; q + 4 <= m; q += 4) {
                int c0 = __shfl(c, q + 0, 16), c1 = __shfl(c, q + 1, 16);
                int c2 = __shfl(c, q + 2, 16), c3 = __shfl(c, q + 3, 16);
                float4 v0 = *(const float4*)&z2[(size_t)c0 * 64 + lane * 4];
                float4 v1 = *(const float4*)&z2[(size_t)c1 * 64 + lane * 4];
                float4 v2 = *(const float4*)&z2[(size_t)c2 * 64 + lane * 4];
                float4 v3 = *(const float4*)&z2[(size_t)c3 * 64 + lane * 4];
                ax += (v0.x + v1.x) + (v2.x + v3.x);
                ay += (v0.y + v1.y) + (v2.y + v3.y);
                az += (v0.z + v1.z) + (v2.z + v3.z);
                aw += (v0.w + v1.w) + (v2.w + v3.w);
            }
            for (; q < m; ++q) {
                int cj = __shfl(c, q, 16);
                float4 v = *(const float4*)&z2[(size_t)cj * 64 + lane * 4];
                ax += v.x; ay += v.y; az += v.z; aw += v.w;
            }
        }
    }
    s[threadIdx.x] = make_float4(ax, ay, az, aw);
    __syncthreads();
    #pragma unroll
    for (int off = 8; off >= 1; off >>= 1) {
        if (grp < off) {
            float4 o = s[(grp + off) * 16 + lane];
            float4 m = s[grp * 16 + lane];
            m.x += o.x; m.y += o.y; m.z += o.z; m.w += o.w;
            s[grp * 16 + lane] = m;
        }
        __syncthreads();
    }
    if (grp == 0) {
        float inv = 1.0f / fmaxf((float)(end - start), 1.0f);
        float4 m = s[lane];
        m.x *= inv; m.y *= inv; m.z *= inv; m.w *= inv;
        *(float4*)&g[(size_t)b * 64 + lane * 4] = m;
    }
}

// out[512,4] = softmax( A[512,1024] @ W[4,1024]^T + bias )
__global__ __launch_bounds__(256) void final_kernel(
    const float* __restrict__ A, const float* __restrict__ W,
    const float* __restrict__ bias, float* __restrict__ out)
{
    int i = blockIdx.x * 256 + threadIdx.x;
    int r = i >> 2, o = i & 3;
    float s = bias[o];
    const float4* a = (const float4*)&A[(size_t)r * 1024];
    const float4* w = (const float4*)&W[(size_t)o * 1024];
    #pragma unroll 4
    for (int k = 0; k < 256; ++k) {
        float4 av = a[k], wv = w[k];
        s += av.x * wv.x + av.y * wv.y + av.z * wv.z + av.w * wv.w;
    }
    float m = s;
    m = fmaxf(m, __shfl_xor(m, 1));
    m = fmaxf(m, __shfl_xor(m, 2));
    float e = __expf(s - m);
    float sum = e;
    sum += __shfl_xor(sum, 1);
    sum += __shfl_xor(sum, 2);
    out[i] = e / sum;
}

extern "C" void kernel_launch(void* const* d_in, const int* in_sizes, int n_in,
                              void* d_out, int out_size, void* d_ws, size_t ws_size,
                              hipStream_t stream)
{
    const float* x     = (const float*)d_in[0];
    const int*   ei    = (const int*)d_in[1];
    const int*   batch = (const int*)d_in[2];
    const float* fc1_w = (const float*)d_in[3];   // [4,32,128] -> [128,128]
    const float* fc2_w = (const float*)d_in[5];   // [1,64,128] -> [64,128]
    const float* w1 = (const float*)d_in[7];  const float* b1 = (const float*)d_in[8];
    const float* w2 = (const float*)d_in[9];  const float* b2 = (const float*)d_in[10];
    const float* w3 = (const float*)d_in[11]; const float* b3 = (const float*)d_in[12];
    const float* w4 = (const float*)d_in[13]; const float* b4 = (const float*)d_in[14];
    const float* w5 = (const float*)d_in[15]; const float* b5 = (const float*)d_in[16];
    float* out = (float*)d_out;

    const int N = 50000, E = 800000, B = 512;
    const int* rowp = ei;        // destinations
    const int* colp = ei + E;    // sources

    // ---- workspace layout ----
    // bufA: gx [N,128] (dead after gemm12) -> a1/a2 (MLP)
    // bufB: ELL (3.2M ints) | z2 (3.2M floats) (dead after pool) -> cpart
    float* ws   = (float*)d_ws;
    float* bufA = ws;
    float* bufB = ws + 6400000;
    float* g    = ws + 12800000;              // 32768 f
    int* cnt    = (int*)(g + 32768);          // 50000
    int* bstart = cnt + 50000;                // 513

    int*   ell   = (int*)bufB;                // 50000*64 ints
    float* z2    = bufB + 3200000;            // 50000*64 floats
    float* a1    = bufA;                      // 524288
    float* a2    = bufA + 524288;             // 524288
    float* cpart = bufB;                      // 8*524288

    // ---- init + ELL build ----
    init_kernel<<<196, 256, 0, stream>>>(batch, cnt, bstart, N, B);
    scatter_ell<<<(E + 255) / 256, 256, 0, stream>>>(rowp, colp, cnt, ell, E);

    // ---- layer 1 gather:  gx = sum_neighbors x ----
    gather_sum_ell<32><<<(N + 7) / 8, 256, 0, stream>>>(ell, cnt, x, bufA, N);

    // ---- fused GEMM1 + ELU + GEMM2:  z2 = elu(gx@W1^T)@W2^T ----
    gemm12_fused<<<782, 256, 0, stream>>>(bufA, fc1_w, fc2_w, z2, N);

    // ---- fused gather2 + mean-pool ----
    pool_gather<<<B, 256, 0, stream>>>(ell, cnt, bstart, z2, g);

    // ---- MLP ----
    gemm256<1, true, false><<<dim3(4, 16, 1), 256, 0, stream>>>(g, w1, b1, a1, 512, 1024, 64, 0);
    gemm256<0, false, true><<<dim3(4, 16, 8), 256, 0, stream>>>(a1, w2, nullptr, cpart, 512, 1024, 1024, 128);
    reduce_bias_relu<<<512, 256, 0, stream>>>(cpart, b2, a2, 131072, 1024, 8);
    gemm256<0, false, true><<<dim3(4, 16, 8), 256, 0, stream>>>(a2, w3, nullptr, cpart, 512, 1024, 1024, 128);
    reduce_bias_relu<<<512, 256, 0, stream>>>(cpart, b3, a1, 131072, 1024, 8);
    gemm256<0, false, true><<<dim3(4, 16, 8), 256, 0, stream>>>(a1, w4, nullptr, cpart, 512, 1024, 1024, 128);
    reduce_bias_relu<<<512, 256, 0, stream>>>(cpart, b4, a2, 131072, 1024, 8);

    // ---- final layer + softmax ----
    final_kernel<<<8, 256, 0, stream>>>(a2, w5, b5, out);
}